// Round 4
// baseline (469.643 us; speedup 1.0000x reference)
//
#include <hip/hip_runtime.h>
#include <hip/hip_bf16.h>

#define H 128

typedef _Float16 f16x4 __attribute__((ext_vector_type(4)));
typedef _Float16 f16x8 __attribute__((ext_vector_type(8)));
typedef float    f32x4 __attribute__((ext_vector_type(4)));

__device__ __forceinline__ float silu_f(float v) {
    return v / (1.0f + __expf(-v));
}

// ---------------------------------------------------------------------------
// Weight pre-pack: 10 matrices [128k][128c] f32 -> fp16 A-frag layout.
// Frag (mat, ct, kb): lane holds m = ct*16+(lane&15), k = kb*32+(lane>>4)*8+j.
// ---------------------------------------------------------------------------
__global__ __launch_bounds__(256)
void pack_w(const float* __restrict__ emb_w, const float* __restrict__ conv_w,
            const float* __restrict__ out_w, _Float16* __restrict__ wpk)
{
    const int gid = blockIdx.x * 256 + threadIdx.x;     // 20480 = 10*2048
    const int mat = gid >> 11;
    const int r   = gid & 2047;
    const int ct  = r >> 8;
    const int kb  = (r >> 6) & 3;
    const int lane = r & 63;
    const float* W = (mat < 4) ? emb_w + mat * 16384
                   : (mat < 8) ? conv_w + (mat - 4) * 16384
                               : out_w + (mat - 8) * 16384;
    const int m  = ct * 16 + (lane & 15);
    const int k0 = kb * 32 + (lane >> 4) * 8;
    _Float16* dst = wpk + (size_t)gid * 8;
#pragma unroll
    for (int j = 0; j < 8; ++j)
        dst[j] = (_Float16)W[(k0 + j) * H + m];
}

// ---------------------------------------------------------------------------
// Fused two-layer dense, col-split: 128-thread block = 2 waves sharing one
// 16-row strip; wave `half` computes out-cols [half*64, half*64+64).
// 2500 blocks -> 5000 waves (4.9/SIMD) for latency hiding.
//   MODE 0: y = mlp2(x);  MODE 1: y = x + mlp2(x);  MODE 2: z=x.*x2, y=z+mlp2(z)
// ---------------------------------------------------------------------------
template <int MODE>
__global__ __launch_bounds__(128)
void mlp2_v3(const float* __restrict__ x, const float* __restrict__ x2,
             const _Float16* __restrict__ wpk,   // 2 packed mats
             const float* __restrict__ b0, const float* __restrict__ b1,
             float* __restrict__ y)
{
    __shared__ _Float16 hs[16 * 136];     // hidden strip, 4.25 KB
    const int tid  = threadIdx.x;
    const int lane = tid & 63;
    const int half = tid >> 6;            // 0/1: out-col half
    const int rl   = lane & 15;
    const int quad = lane >> 4;
    const int row  = blockIdx.x * 16 + rl;
    const size_t rbase = (size_t)row * H;

    f32x4 acc[4];
#pragma unroll
    for (int c = 0; c < 4; ++c) acc[c] = (f32x4){0.f, 0.f, 0.f, 0.f};

    // ---- layer 1: B-frags from global x ----
#pragma unroll
    for (int kb = 0; kb < 4; ++kb) {
        const int kc = kb * 32 + quad * 8;
        float4 v0 = *(const float4*)(x + rbase + kc);
        float4 v1 = *(const float4*)(x + rbase + kc + 4);
        if (MODE == 2) {
            float4 u0 = *(const float4*)(x2 + rbase + kc);
            float4 u1 = *(const float4*)(x2 + rbase + kc + 4);
            v0.x *= u0.x; v0.y *= u0.y; v0.z *= u0.z; v0.w *= u0.w;
            v1.x *= u1.x; v1.y *= u1.y; v1.z *= u1.z; v1.w *= u1.w;
        }
        f16x8 bf = {(_Float16)v0.x, (_Float16)v0.y, (_Float16)v0.z, (_Float16)v0.w,
                    (_Float16)v1.x, (_Float16)v1.y, (_Float16)v1.z, (_Float16)v1.w};
#pragma unroll
        for (int ctl = 0; ctl < 4; ++ctl) {
            const int ct = half * 4 + ctl;
            f16x8 af = *(const f16x8*)(wpk + ((size_t)(ct * 4 + kb) * 64 + lane) * 8);
            acc[ctl] = __builtin_amdgcn_mfma_f32_16x16x32_f16(af, bf, acc[ctl], 0, 0, 0);
        }
    }

    // ---- hidden = silu(acc+b0) -> LDS strip ----
#pragma unroll
    for (int ctl = 0; ctl < 4; ++ctl) {
        const int c = (half * 4 + ctl) * 16 + quad * 4;
        float4 bb = *(const float4*)(b0 + c);
        f16x4 hv = {(_Float16)silu_f(acc[ctl][0] + bb.x),
                    (_Float16)silu_f(acc[ctl][1] + bb.y),
                    (_Float16)silu_f(acc[ctl][2] + bb.z),
                    (_Float16)silu_f(acc[ctl][3] + bb.w)};
        *(f16x4*)(hs + rl * 136 + c) = hv;
    }
    __syncthreads();

    // ---- layer 2 ----
#pragma unroll
    for (int c = 0; c < 4; ++c) acc[c] = (f32x4){0.f, 0.f, 0.f, 0.f};
#pragma unroll
    for (int kb = 0; kb < 4; ++kb) {
        f16x8 bf = *(const f16x8*)(hs + rl * 136 + kb * 32 + quad * 8);
#pragma unroll
        for (int ctl = 0; ctl < 4; ++ctl) {
            const int ct = half * 4 + ctl;
            f16x8 af = *(const f16x8*)(wpk + 16384 +
                                       ((size_t)(ct * 4 + kb) * 64 + lane) * 8);
            acc[ctl] = __builtin_amdgcn_mfma_f32_16x16x32_f16(af, bf, acc[ctl], 0, 0, 0);
        }
    }

    // ---- epilogue ----
#pragma unroll
    for (int ctl = 0; ctl < 4; ++ctl) {
        const int c = (half * 4 + ctl) * 16 + quad * 4;
        float4 bb = *(const float4*)(b1 + c);
        float4 v;
        v.x = silu_f(acc[ctl][0] + bb.x);
        v.y = silu_f(acc[ctl][1] + bb.y);
        v.z = silu_f(acc[ctl][2] + bb.z);
        v.w = silu_f(acc[ctl][3] + bb.w);
        if (MODE == 1) {
            float4 rv = *(const float4*)(x + rbase + c);
            v.x += rv.x; v.y += rv.y; v.z += rv.z; v.w += rv.w;
        } else if (MODE == 2) {
            float4 ra = *(const float4*)(x + rbase + c);
            float4 rb = *(const float4*)(x2 + rbase + c);
            v.x += ra.x * rb.x; v.y += ra.y * rb.y;
            v.z += ra.z * rb.z; v.w += ra.w * rb.w;
        }
        *(float4*)(y + rbase + c) = v;
    }
}

// ---------------------------------------------------------------------------
// Counting sort of edges by destination node (flat key = b*N + row)
// ---------------------------------------------------------------------------
__global__ __launch_bounds__(256)
void hist_k(const int* __restrict__ eidx, int* __restrict__ cnt)
{
    const int e = blockIdx.x * 256 + threadIdx.x;       // 640000 exact
    const int row = eidx[2 * (size_t)e];
    const int b = (unsigned)e / 160000u;
    atomicAdd(&cnt[b * 10000 + row], 1);
}

__global__ void scan_a(const int* __restrict__ cnt, int* __restrict__ psum)
{
    __shared__ int sh[1024];
    const int tid = threadIdx.x;
    sh[tid] = cnt[blockIdx.x * 1024 + tid];
    __syncthreads();
    for (int s = 512; s > 0; s >>= 1) {
        if (tid < s) sh[tid] += sh[tid + s];
        __syncthreads();
    }
    if (tid == 0) psum[blockIdx.x] = sh[0];
}

__global__ void scan_b(int* __restrict__ psum)
{
    if (threadIdx.x == 0) {
        int run = 0;
        for (int i = 0; i < 40; ++i) { int t = psum[i]; psum[i] = run; run += t; }
    }
}

__global__ void scan_c(const int* __restrict__ cnt, const int* __restrict__ psum,
                       int* __restrict__ offs, int* __restrict__ cursor)
{
    __shared__ int sh[1024];
    const int tid = threadIdx.x;
    const int i = blockIdx.x * 1024 + tid;
    const int v = cnt[i];
    sh[tid] = v;
    __syncthreads();
    for (int s = 1; s < 1024; s <<= 1) {
        int t = (tid >= s) ? sh[tid - s] : 0;
        __syncthreads();
        sh[tid] += t;
        __syncthreads();
    }
    const int excl = sh[tid] - v + psum[blockIdx.x];
    offs[i] = excl;
    cursor[i] = excl;
    if (i == 40959) offs[40960] = excl + v;
}

__global__ __launch_bounds__(256)
void scatter_k(const int* __restrict__ eidx, int* __restrict__ cursor,
               int2* __restrict__ meta)
{
    const int e = blockIdx.x * 256 + threadIdx.x;       // 640000 exact
    const int2 rc = ((const int2*)eidx)[e];
    const int b = (unsigned)e / 160000u;
    const int pos = atomicAdd(&cursor[b * 10000 + rc.x], 1);
    meta[pos] = make_int2(e, b * 10000 + rc.y);
}

// ---------------------------------------------------------------------------
// Gather-reduce v3: 1 wave per node, lane covers h = {2l, 2l+1}; 10 nodes per
// wave (imbalance averaging); edge metadata batched via readlane broadcast.
// ---------------------------------------------------------------------------
__global__ __launch_bounds__(256)
void conv_k(const float* __restrict__ ef, const float* __restrict__ sdst,
            const float* __restrict__ ew, const float* __restrict__ C,
            const int* __restrict__ offs, const int2* __restrict__ meta,
            float* __restrict__ conv)
{
    const int lane = threadIdx.x & 63;
    const int wid  = threadIdx.x >> 6;
    const int n0   = (blockIdx.x * 4 + wid) * 10;   // 1000 blocks -> 4000 waves

    float2 ewr[32];
#pragma unroll
    for (int k = 0; k < 32; ++k)
        ewr[k] = *(const float2*)(ew + k * H + lane * 2);

    const float* sg = sdst + lane * 2;

    for (int t = 0; t < 10; ++t) {
        const int nid = n0 + t;
        const int start = offs[nid], end = offs[nid + 1];
        float acc0 = 0.f, acc1 = 0.f;
        for (int base = start; base < end; base += 64) {
            const int cnt = min(64, end - base);
            int2 md = make_int2(0, 0);
            if (lane < cnt) md = meta[base + lane];
            for (int j = 0; j < cnt; ++j) {
                const int e  = __builtin_amdgcn_readlane(md.x, j);
                const int sc = __builtin_amdgcn_readlane(md.y, j);
                const float2 g = *(const float2*)(sg + (size_t)sc * H);
                const float4* ep = (const float4*)(ef + (size_t)e * 32);
                float p0a = 0.f, p0b = 0.f, p1a = 0.f, p1b = 0.f;
#pragma unroll
                for (int kb = 0; kb < 8; ++kb) {
                    float4 q = ep[kb];
                    p0a = fmaf(q.x, ewr[kb * 4 + 0].x, p0a);
                    p1a = fmaf(q.x, ewr[kb * 4 + 0].y, p1a);
                    p0b = fmaf(q.y, ewr[kb * 4 + 1].x, p0b);
                    p1b = fmaf(q.y, ewr[kb * 4 + 1].y, p1b);
                    p0a = fmaf(q.z, ewr[kb * 4 + 2].x, p0a);
                    p1a = fmaf(q.z, ewr[kb * 4 + 2].y, p1a);
                    p0b = fmaf(q.w, ewr[kb * 4 + 3].x, p0b);
                    p1b = fmaf(q.w, ewr[kb * 4 + 3].y, p1b);
                }
                acc0 = fmaf(g.x, p0a + p0b, acc0);
                acc1 = fmaf(g.y, p1a + p1b, acc1);
            }
        }
        const float Cb = C[(unsigned)nid / 10000u];
        float2 st = make_float2(acc0 * Cb, acc1 * Cb);
        *(float2*)(conv + (size_t)nid * H + lane * 2) = st;
    }
}

// ---------------------------------------------------------------------------
extern "C" void kernel_launch(void* const* d_in, const int* in_sizes, int n_in,
                              void* d_out, int out_size, void* d_ws, size_t ws_size,
                              hipStream_t stream)
{
    const float* scalar = (const float*)d_in[0];
    const float* ef     = (const float*)d_in[1];
    const int*   eidx   = (const int*)d_in[2];
    const float* C      = (const float*)d_in[3];
    const float* emb_w  = (const float*)d_in[4];
    const float* emb_b  = (const float*)d_in[5];
    const float* e_w    = (const float*)d_in[6];
    const float* conv_w = (const float*)d_in[7];
    const float* conv_b = (const float*)d_in[8];
    const float* out_w  = (const float*)d_in[9];
    const float* out_b  = (const float*)d_in[10];

    const int M = 40000;
    const size_t nodeElems = (size_t)M * H;            // 5,120,000

    float* s2s  = (float*)d_ws;
    float* sdst = s2s + nodeElems;
    float* conv = sdst + nodeElems;
    _Float16* wpk = (_Float16*)(conv + nodeElems);     // 163840 halves
    int* cnt    = (int*)(wpk + 163840);                // 40960
    int* psum   = cnt + 40960;                         // 64
    int* offs   = psum + 64;                           // 40964
    int* cursor = offs + 40964;                        // 40960
    int2* meta  = (int2*)(cursor + 40960);             // 640000 int2 (8B-aligned)

    const int HH = H * H;
    dim3 blk(256);
    dim3 blk128(128);

    pack_w<<<80, blk, 0, stream>>>(emb_w, conv_w, out_w, wpk);
    hipMemsetAsync(cnt, 0, 40960 * sizeof(int), stream);

    // s2s = Dense(Dense(scalar; emb[0,0]); emb[0,1])
    mlp2_v3<0><<<2500, blk128, 0, stream>>>(scalar, nullptr, wpk,
                                            emb_b, emb_b + H, s2s);
    // scalar_dst
    mlp2_v3<0><<<2500, blk128, 0, stream>>>(scalar, nullptr, wpk + 2 * HH,
                                            emb_b + 2 * H, emb_b + 3 * H, sdst);
    // counting sort of edges by destination
    hist_k<<<2500, blk, 0, stream>>>(eidx, cnt);
    scan_a<<<40, 1024, 0, stream>>>(cnt, psum);
    scan_b<<<1, 64, 0, stream>>>(psum);
    scan_c<<<40, 1024, 0, stream>>>(cnt, psum, offs, cursor);
    scatter_k<<<2500, blk, 0, stream>>>(eidx, cursor, meta);
    // conv = C * segment_sum(gather(sdst,col) * ef@e_w, row)
    conv_k<<<1000, blk, 0, stream>>>(ef, sdst, e_w, C, offs, meta, conv);
    // conv = residual(conv; conv_w[0]); residual(conv; conv_w[1])
    mlp2_v3<1><<<2500, blk128, 0, stream>>>(conv, nullptr, wpk + 4 * HH,
                                            conv_b, conv_b + H, conv);
    mlp2_v3<1><<<2500, blk128, 0, stream>>>(conv, nullptr, wpk + 6 * HH,
                                            conv_b + 2 * H, conv_b + 3 * H, conv);
    // out = residual(s2s .* conv; out_w)
    mlp2_v3<2><<<2500, blk128, 0, stream>>>(s2s, conv, wpk + 8 * HH,
                                            out_b, out_b + H, (float*)d_out);
}

// Round 5
// 409.830 us; speedup vs baseline: 1.1459x; 1.1459x over previous
//
#include <hip/hip_runtime.h>
#include <hip/hip_bf16.h>

#define H 128

typedef _Float16 f16x4 __attribute__((ext_vector_type(4)));
typedef _Float16 f16x8 __attribute__((ext_vector_type(8)));
typedef float    f32x4 __attribute__((ext_vector_type(4)));
typedef float    f32x2 __attribute__((ext_vector_type(2)));

__device__ __forceinline__ float silu_f(float v) {
    return v / (1.0f + __expf(-v));
}

// ---------------------------------------------------------------------------
// Weight pre-pack: 10 matrices [128k][128c] f32 -> fp16 A-frag layout.
// Frag (mat, ct, kb): lane holds m = ct*16+(lane&15), k = kb*32+(lane>>4)*8+j.
// mats 0-3 = emb_w, 4-7 = conv_w, 8-9 = out_w.
// ---------------------------------------------------------------------------
__global__ __launch_bounds__(256)
void pack_w(const float* __restrict__ emb_w, const float* __restrict__ conv_w,
            const float* __restrict__ out_w, _Float16* __restrict__ wpk)
{
    const int gid = blockIdx.x * 256 + threadIdx.x;     // 20480 = 10*2048
    const int mat = gid >> 11;
    const int r   = gid & 2047;
    const int ct  = r >> 8;
    const int kb  = (r >> 6) & 3;
    const int lane = r & 63;
    const float* W = (mat < 4) ? emb_w + mat * 16384
                   : (mat < 8) ? conv_w + (mat - 4) * 16384
                               : out_w + (mat - 8) * 16384;
    const int m  = ct * 16 + (lane & 15);
    const int k0 = kb * 32 + (lane >> 4) * 8;
    _Float16* dst = wpk + (size_t)gid * 8;
#pragma unroll
    for (int j = 0; j < 8; ++j)
        dst[j] = (_Float16)W[(k0 + j) * H + m];
}

// ---------------------------------------------------------------------------
// MFMA layer helpers (col-split: wave `half` covers out-cols [half*64, +64)).
// ---------------------------------------------------------------------------
__device__ __forceinline__ void mfma_layer(const _Float16* __restrict__ w,
                                           const f16x8 bf[4], int half, int lane,
                                           f32x4 acc[4])
{
#pragma unroll
    for (int c = 0; c < 4; ++c) acc[c] = (f32x4){0.f, 0.f, 0.f, 0.f};
#pragma unroll
    for (int kb = 0; kb < 4; ++kb) {
#pragma unroll
        for (int ctl = 0; ctl < 4; ++ctl) {
            const int ct = half * 4 + ctl;
            f16x8 af = *(const f16x8*)(w + ((size_t)(ct * 4 + kb) * 64 + lane) * 8);
            acc[ctl] = __builtin_amdgcn_mfma_f32_16x16x32_f16(af, bf[kb], acc[ctl], 0, 0, 0);
        }
    }
}

__device__ __forceinline__ void store_strip(_Float16* strip, const f32x4 acc[4],
                                            const float* bias, int half, int rl, int quad)
{
#pragma unroll
    for (int ctl = 0; ctl < 4; ++ctl) {
        const int c = (half * 4 + ctl) * 16 + quad * 4;
        float4 bb = *(const float4*)(bias + c);
        f16x4 hv = {(_Float16)silu_f(acc[ctl][0] + bb.x),
                    (_Float16)silu_f(acc[ctl][1] + bb.y),
                    (_Float16)silu_f(acc[ctl][2] + bb.z),
                    (_Float16)silu_f(acc[ctl][3] + bb.w)};
        *(f16x4*)(strip + rl * 136 + c) = hv;
    }
}

__device__ __forceinline__ void store_strip_raw(_Float16* strip, const f32x4 t[4],
                                                int half, int rl, int quad)
{
#pragma unroll
    for (int ctl = 0; ctl < 4; ++ctl) {
        const int c = (half * 4 + ctl) * 16 + quad * 4;
        f16x4 hv = {(_Float16)t[ctl][0], (_Float16)t[ctl][1],
                    (_Float16)t[ctl][2], (_Float16)t[ctl][3]};
        *(f16x4*)(strip + rl * 136 + c) = hv;
    }
}

__device__ __forceinline__ void load_bf(const _Float16* strip, f16x8 bf[4],
                                        int rl, int quad)
{
#pragma unroll
    for (int kb = 0; kb < 4; ++kb)
        bf[kb] = *(const f16x8*)(strip + rl * 136 + kb * 32 + quad * 8);
}

// ---------------------------------------------------------------------------
// emb2_k: s2s = mlp2(x; mats 0,1), sdst = mlp2(x; mats 2,3) — x read ONCE.
// 128-thread block = 2 waves sharing one 16-row strip, col-split.
// ---------------------------------------------------------------------------
__global__ __launch_bounds__(128)
void emb2_k(const float* __restrict__ x, const _Float16* __restrict__ wpk,
            const float* __restrict__ emb_b,
            float* __restrict__ s2s, float* __restrict__ sdst)
{
    __shared__ _Float16 hsA[16 * 136], hsB[16 * 136];
    const int tid  = threadIdx.x;
    const int lane = tid & 63;
    const int half = tid >> 6;
    const int rl   = lane & 15;
    const int quad = lane >> 4;
    const int row  = blockIdx.x * 16 + rl;
    const size_t rbase = (size_t)row * H;

    f16x8 bf[4];
#pragma unroll
    for (int kb = 0; kb < 4; ++kb) {
        const int kc = kb * 32 + quad * 8;
        float4 v0 = *(const float4*)(x + rbase + kc);
        float4 v1 = *(const float4*)(x + rbase + kc + 4);
        bf[kb] = (f16x8){(_Float16)v0.x, (_Float16)v0.y, (_Float16)v0.z, (_Float16)v0.w,
                         (_Float16)v1.x, (_Float16)v1.y, (_Float16)v1.z, (_Float16)v1.w};
    }

    f32x4 acc[4];
    mfma_layer(wpk, bf, half, lane, acc);                 // s2s layer1 (mat0)
    store_strip(hsA, acc, emb_b, half, rl, quad);
    mfma_layer(wpk + 2 * 16384, bf, half, lane, acc);     // sdst layer1 (mat2)
    store_strip(hsB, acc, emb_b + 2 * H, half, rl, quad);
    __syncthreads();

    f16x8 bfA[4], bfB[4];
    load_bf(hsA, bfA, rl, quad);
    load_bf(hsB, bfB, rl, quad);

    mfma_layer(wpk + 16384, bfA, half, lane, acc);        // s2s layer2 (mat1)
#pragma unroll
    for (int ctl = 0; ctl < 4; ++ctl) {
        const int c = (half * 4 + ctl) * 16 + quad * 4;
        float4 bb = *(const float4*)(emb_b + H + c);
        float4 v;
        v.x = silu_f(acc[ctl][0] + bb.x);
        v.y = silu_f(acc[ctl][1] + bb.y);
        v.z = silu_f(acc[ctl][2] + bb.z);
        v.w = silu_f(acc[ctl][3] + bb.w);
        *(float4*)(s2s + rbase + c) = v;
    }
    mfma_layer(wpk + 3 * 16384, bfB, half, lane, acc);    // sdst layer2 (mat3)
#pragma unroll
    for (int ctl = 0; ctl < 4; ++ctl) {
        const int c = (half * 4 + ctl) * 16 + quad * 4;
        float4 bb = *(const float4*)(emb_b + 3 * H + c);
        float4 v;
        v.x = silu_f(acc[ctl][0] + bb.x);
        v.y = silu_f(acc[ctl][1] + bb.y);
        v.z = silu_f(acc[ctl][2] + bb.z);
        v.w = silu_f(acc[ctl][3] + bb.w);
        *(float4*)(sdst + rbase + c) = v;
    }
}

// ---------------------------------------------------------------------------
// out6_k: fused tail — conv -> residual(conv_w0) -> residual(conv_w1)
//                      -> z = s2s .* conv -> out = z + mlp2(z; out_w)
// 6 MFMA layers per 16-row strip; activations ping-pong via 2 LDS strips.
// ---------------------------------------------------------------------------
__global__ __launch_bounds__(128)
void out6_k(const float* __restrict__ conv, const float* __restrict__ s2s,
            const _Float16* __restrict__ w6,   // mats 4..9 (6 * 16384 halves)
            const float* __restrict__ conv_b, const float* __restrict__ out_b,
            float* __restrict__ y)
{
    __shared__ _Float16 hs0[16 * 136], hs1[16 * 136];
    const int tid  = threadIdx.x;
    const int lane = tid & 63;
    const int half = tid >> 6;
    const int rl   = lane & 15;
    const int quad = lane >> 4;
    const int row  = blockIdx.x * 16 + rl;
    const size_t rbase = (size_t)row * H;

    f16x8 bf[4];
#pragma unroll
    for (int kb = 0; kb < 4; ++kb) {
        const int kc = kb * 32 + quad * 8;
        float4 v0 = *(const float4*)(conv + rbase + kc);
        float4 v1 = *(const float4*)(conv + rbase + kc + 4);
        bf[kb] = (f16x8){(_Float16)v0.x, (_Float16)v0.y, (_Float16)v0.z, (_Float16)v0.w,
                         (_Float16)v1.x, (_Float16)v1.y, (_Float16)v1.z, (_Float16)v1.w};
    }

    f32x4 acc[4], tD[4];

    // L0: hidden of residual-1
    mfma_layer(w6, bf, half, lane, acc);
    store_strip(hs0, acc, conv_b, half, rl, quad);
    __syncthreads();
    load_bf(hs0, bf, rl, quad);

    // L1: t = conv + mlp2_out  (D-layout regs)
    mfma_layer(w6 + 16384, bf, half, lane, acc);
#pragma unroll
    for (int ctl = 0; ctl < 4; ++ctl) {
        const int c = (half * 4 + ctl) * 16 + quad * 4;
        float4 bb = *(const float4*)(conv_b + H + c);
        float4 cv = *(const float4*)(conv + rbase + c);
        tD[ctl][0] = cv.x + silu_f(acc[ctl][0] + bb.x);
        tD[ctl][1] = cv.y + silu_f(acc[ctl][1] + bb.y);
        tD[ctl][2] = cv.z + silu_f(acc[ctl][2] + bb.z);
        tD[ctl][3] = cv.w + silu_f(acc[ctl][3] + bb.w);
    }
    store_strip_raw(hs1, tD, half, rl, quad);
    __syncthreads();
    load_bf(hs1, bf, rl, quad);

    // L2: hidden of residual-2
    mfma_layer(w6 + 2 * 16384, bf, half, lane, acc);
    store_strip(hs0, acc, conv_b + 2 * H, half, rl, quad);
    __syncthreads();
    load_bf(hs0, bf, rl, quad);

    // L3: t += out;  z = t * s2s
    mfma_layer(w6 + 3 * 16384, bf, half, lane, acc);
#pragma unroll
    for (int ctl = 0; ctl < 4; ++ctl) {
        const int c = (half * 4 + ctl) * 16 + quad * 4;
        float4 bb = *(const float4*)(conv_b + 3 * H + c);
        float4 sv = *(const float4*)(s2s + rbase + c);
        tD[ctl][0] = (tD[ctl][0] + silu_f(acc[ctl][0] + bb.x)) * sv.x;
        tD[ctl][1] = (tD[ctl][1] + silu_f(acc[ctl][1] + bb.y)) * sv.y;
        tD[ctl][2] = (tD[ctl][2] + silu_f(acc[ctl][2] + bb.z)) * sv.z;
        tD[ctl][3] = (tD[ctl][3] + silu_f(acc[ctl][3] + bb.w)) * sv.w;
    }
    store_strip_raw(hs1, tD, half, rl, quad);
    __syncthreads();
    load_bf(hs1, bf, rl, quad);

    // L4: hidden of final residual
    mfma_layer(w6 + 4 * 16384, bf, half, lane, acc);
    store_strip(hs0, acc, out_b, half, rl, quad);
    __syncthreads();
    load_bf(hs0, bf, rl, quad);

    // L5: out = z + mlp2_out
    mfma_layer(w6 + 5 * 16384, bf, half, lane, acc);
#pragma unroll
    for (int ctl = 0; ctl < 4; ++ctl) {
        const int c = (half * 4 + ctl) * 16 + quad * 4;
        float4 bb = *(const float4*)(out_b + H + c);
        float4 v;
        v.x = tD[ctl][0] + silu_f(acc[ctl][0] + bb.x);
        v.y = tD[ctl][1] + silu_f(acc[ctl][1] + bb.y);
        v.z = tD[ctl][2] + silu_f(acc[ctl][2] + bb.z);
        v.w = tD[ctl][3] + silu_f(acc[ctl][3] + bb.w);
        *(float4*)(y + rbase + c) = v;
    }
}

// ---------------------------------------------------------------------------
// Counting sort of edges by destination node (flat key = b*N + row)
// ---------------------------------------------------------------------------
__global__ __launch_bounds__(256)
void hist_k(const int* __restrict__ eidx, int* __restrict__ cnt)
{
    const int e = blockIdx.x * 256 + threadIdx.x;       // 640000 exact
    const int row = eidx[2 * (size_t)e];
    const int b = (unsigned)e / 160000u;
    atomicAdd(&cnt[b * 10000 + row], 1);
}

__global__ void scan_a(const int* __restrict__ cnt, int* __restrict__ psum)
{
    __shared__ int sh[1024];
    const int tid = threadIdx.x;
    sh[tid] = cnt[blockIdx.x * 1024 + tid];
    __syncthreads();
    for (int s = 512; s > 0; s >>= 1) {
        if (tid < s) sh[tid] += sh[tid + s];
        __syncthreads();
    }
    if (tid == 0) psum[blockIdx.x] = sh[0];
}

__global__ void scan_b(int* __restrict__ psum)
{
    if (threadIdx.x == 0) {
        int run = 0;
        for (int i = 0; i < 40; ++i) { int t = psum[i]; psum[i] = run; run += t; }
    }
}

__global__ void scan_c(const int* __restrict__ cnt, const int* __restrict__ psum,
                       int* __restrict__ offs, int* __restrict__ cursor)
{
    __shared__ int sh[1024];
    const int tid = threadIdx.x;
    const int i = blockIdx.x * 1024 + tid;
    const int v = cnt[i];
    sh[tid] = v;
    __syncthreads();
    for (int s = 1; s < 1024; s <<= 1) {
        int t = (tid >= s) ? sh[tid - s] : 0;
        __syncthreads();
        sh[tid] += t;
        __syncthreads();
    }
    const int excl = sh[tid] - v + psum[blockIdx.x];
    offs[i] = excl;
    cursor[i] = excl;
    if (i == 40959) offs[40960] = excl + v;
}

__global__ __launch_bounds__(256)
void scatter_k(const int* __restrict__ eidx, int* __restrict__ cursor,
               int2* __restrict__ meta)
{
    const int e = blockIdx.x * 256 + threadIdx.x;       // 640000 exact
    const int2 rc = ((const int2*)eidx)[e];
    const int b = (unsigned)e / 160000u;
    const int pos = atomicAdd(&cursor[b * 10000 + rc.x], 1);
    meta[pos] = make_int2(e, b * 10000 + rc.y);
}

// ---------------------------------------------------------------------------
// Gather-reduce v4: 1 wave per node (40000 waves for TLP), lane covers
// h = {2l, 2l+1}; metadata batched via readlane; f32x2 packed math.
// ---------------------------------------------------------------------------
__global__ __launch_bounds__(256)
void conv_k(const float* __restrict__ ef, const float* __restrict__ sdst,
            const float* __restrict__ ew, const float* __restrict__ C,
            const int* __restrict__ offs, const int2* __restrict__ meta,
            float* __restrict__ conv)
{
    const int lane = threadIdx.x & 63;
    const int nid  = blockIdx.x * 4 + (threadIdx.x >> 6);   // 10000 blocks

    f32x2 ewr[32];
#pragma unroll
    for (int k = 0; k < 32; ++k)
        ewr[k] = *(const f32x2*)(ew + k * H + lane * 2);

    const int start = offs[nid], end = offs[nid + 1];
    f32x2 acc = {0.f, 0.f};
    for (int base = start; base < end; base += 64) {
        const int cnt = min(64, end - base);
        int2 md = make_int2(0, 0);
        if (lane < cnt) md = meta[base + lane];
        for (int j = 0; j < cnt; ++j) {
            const int e  = __builtin_amdgcn_readlane(md.x, j);
            const int sc = __builtin_amdgcn_readlane(md.y, j);
            const f32x2 g = *(const f32x2*)(sdst + (size_t)sc * H + lane * 2);
            const float4* ep = (const float4*)(ef + (size_t)e * 32);
            f32x2 p0 = {0.f, 0.f}, p1 = {0.f, 0.f};
            f32x2 p2 = {0.f, 0.f}, p3 = {0.f, 0.f};
#pragma unroll
            for (int kb = 0; kb < 8; ++kb) {
                float4 q = ep[kb];
                p0 += (f32x2){q.x, q.x} * ewr[kb * 4 + 0];
                p1 += (f32x2){q.y, q.y} * ewr[kb * 4 + 1];
                p2 += (f32x2){q.z, q.z} * ewr[kb * 4 + 2];
                p3 += (f32x2){q.w, q.w} * ewr[kb * 4 + 3];
            }
            acc += g * ((p0 + p1) + (p2 + p3));
        }
    }
    const float Cb = C[(unsigned)nid / 10000u];
    f32x2 st = acc * Cb;
    *(f32x2*)(conv + (size_t)nid * H + lane * 2) = st;
}

// ---------------------------------------------------------------------------
extern "C" void kernel_launch(void* const* d_in, const int* in_sizes, int n_in,
                              void* d_out, int out_size, void* d_ws, size_t ws_size,
                              hipStream_t stream)
{
    const float* scalar = (const float*)d_in[0];
    const float* ef     = (const float*)d_in[1];
    const int*   eidx   = (const int*)d_in[2];
    const float* C      = (const float*)d_in[3];
    const float* emb_w  = (const float*)d_in[4];
    const float* emb_b  = (const float*)d_in[5];
    const float* e_w    = (const float*)d_in[6];
    const float* conv_w = (const float*)d_in[7];
    const float* conv_b = (const float*)d_in[8];
    const float* out_w  = (const float*)d_in[9];
    const float* out_b  = (const float*)d_in[10];

    const int M = 40000;
    const size_t nodeElems = (size_t)M * H;            // 5,120,000

    float* s2s  = (float*)d_ws;
    float* sdst = s2s + nodeElems;
    float* conv = sdst + nodeElems;
    _Float16* wpk = (_Float16*)(conv + nodeElems);     // 163840 halves
    int* cnt    = (int*)(wpk + 163840);                // 40960
    int* psum   = cnt + 40960;                         // 64
    int* offs   = psum + 64;                           // 40964
    int* cursor = offs + 40964;                        // 40960
    int2* meta  = (int2*)(cursor + 40960);             // 640000 int2

    dim3 blk(256);
    dim3 blk128(128);

    pack_w<<<80, blk, 0, stream>>>(emb_w, conv_w, out_w, wpk);
    hipMemsetAsync(cnt, 0, 40960 * sizeof(int), stream);

    // s2s + scalar_dst in one pass (scalar read once)
    emb2_k<<<2500, blk128, 0, stream>>>(scalar, wpk, emb_b, s2s, sdst);
    // counting sort of edges by destination
    hist_k<<<2500, blk, 0, stream>>>(eidx, cnt);
    scan_a<<<40, 1024, 0, stream>>>(cnt, psum);
    scan_b<<<1, 64, 0, stream>>>(psum);
    scan_c<<<40, 1024, 0, stream>>>(cnt, psum, offs, cursor);
    scatter_k<<<2500, blk, 0, stream>>>(eidx, cursor, meta);
    // conv = C * segment_sum(gather(sdst,col) * ef@e_w, row)
    conv_k<<<10000, blk, 0, stream>>>(ef, sdst, e_w, C, offs, meta, conv);
    // fused tail: residuals + mul + final residual
    out6_k<<<2500, blk128, 0, stream>>>(conv, s2s, wpk + 4 * 16384,
                                        conv_b, out_b, (float*)d_out);
}

// Round 6
// 408.207 us; speedup vs baseline: 1.1505x; 1.0040x over previous
//
#include <hip/hip_runtime.h>
#include <hip/hip_bf16.h>

#define H 128

typedef _Float16 f16x4 __attribute__((ext_vector_type(4)));
typedef _Float16 f16x8 __attribute__((ext_vector_type(8)));
typedef float    f32x4 __attribute__((ext_vector_type(4)));
typedef float    f32x2 __attribute__((ext_vector_type(2)));

__device__ __forceinline__ float silu_f(float v) {
    return v / (1.0f + __expf(-v));
}

// ---------------------------------------------------------------------------
// Weight pre-pack: 10 matrices [128k][128c] f32 -> fp16 A-frag layout.
// Frag (mat, ct, kb): lane holds m = ct*16+(lane&15), k = kb*32+(lane>>4)*8+j.
// Also zeroes the 40960-entry histogram (cnt) for the sort.
// ---------------------------------------------------------------------------
__global__ __launch_bounds__(256)
void pack_w(const float* __restrict__ emb_w, const float* __restrict__ conv_w,
            const float* __restrict__ out_w, _Float16* __restrict__ wpk,
            int* __restrict__ cnt)
{
    const int gid = blockIdx.x * 256 + threadIdx.x;     // 20480 = 10*2048
    cnt[gid] = 0;
    cnt[gid + 20480] = 0;
    const int mat = gid >> 11;
    const int r   = gid & 2047;
    const int ct  = r >> 8;
    const int kb  = (r >> 6) & 3;
    const int lane = r & 63;
    const float* W = (mat < 4) ? emb_w + mat * 16384
                   : (mat < 8) ? conv_w + (mat - 4) * 16384
                               : out_w + (mat - 8) * 16384;
    const int m  = ct * 16 + (lane & 15);
    const int k0 = kb * 32 + (lane >> 4) * 8;
    _Float16* dst = wpk + (size_t)gid * 8;
#pragma unroll
    for (int j = 0; j < 8; ++j)
        dst[j] = (_Float16)W[(k0 + j) * H + m];
}

// ---------------------------------------------------------------------------
// MFMA helpers. CT = 16-col tiles per wave, ct0 = wave's first tile.
// ---------------------------------------------------------------------------
template <int CT>
__device__ __forceinline__ void mfma_layerT(const _Float16* __restrict__ w,
                                            const f16x8 bf[4], int ct0, int lane,
                                            f32x4 acc[CT])
{
#pragma unroll
    for (int c = 0; c < CT; ++c) acc[c] = (f32x4){0.f, 0.f, 0.f, 0.f};
#pragma unroll
    for (int kb = 0; kb < 4; ++kb) {
#pragma unroll
        for (int ctl = 0; ctl < CT; ++ctl) {
            f16x8 af = *(const f16x8*)(w + ((size_t)((ct0 + ctl) * 4 + kb) * 64 + lane) * 8);
            acc[ctl] = __builtin_amdgcn_mfma_f32_16x16x32_f16(af, bf[kb], acc[ctl], 0, 0, 0);
        }
    }
}

template <int CT>
__device__ __forceinline__ void store_stripT(_Float16* strip, const f32x4 acc[CT],
                                             const float* bias, int ct0, int rl, int quad)
{
#pragma unroll
    for (int ctl = 0; ctl < CT; ++ctl) {
        const int c = (ct0 + ctl) * 16 + quad * 4;
        float4 bb = *(const float4*)(bias + c);
        f16x4 hv = {(_Float16)silu_f(acc[ctl][0] + bb.x),
                    (_Float16)silu_f(acc[ctl][1] + bb.y),
                    (_Float16)silu_f(acc[ctl][2] + bb.z),
                    (_Float16)silu_f(acc[ctl][3] + bb.w)};
        *(f16x4*)(strip + rl * 136 + c) = hv;
    }
}

template <int CT>
__device__ __forceinline__ void store_strip_rawT(_Float16* strip, const f32x4 t[CT],
                                                 int ct0, int rl, int quad)
{
#pragma unroll
    for (int ctl = 0; ctl < CT; ++ctl) {
        const int c = (ct0 + ctl) * 16 + quad * 4;
        f16x4 hv = {(_Float16)t[ctl][0], (_Float16)t[ctl][1],
                    (_Float16)t[ctl][2], (_Float16)t[ctl][3]};
        *(f16x4*)(strip + rl * 136 + c) = hv;
    }
}

__device__ __forceinline__ void load_bf(const _Float16* strip, f16x8 bf[4],
                                        int rl, int quad)
{
#pragma unroll
    for (int kb = 0; kb < 4; ++kb)
        bf[kb] = *(const f16x8*)(strip + rl * 136 + kb * 32 + quad * 8);
}

// ---------------------------------------------------------------------------
// emb2_k: s2s = mlp2(x; mats 0,1), sdst = mlp2(x; mats 2,3), x read once.
// 256-thread block = 4 waves on one 16-row strip:
//   wave = (msel = wid>>1 selects matrix pair, half = wid&1 selects col half)
// ---------------------------------------------------------------------------
__global__ __launch_bounds__(256)
void emb2_k(const float* __restrict__ x, const _Float16* __restrict__ wpk,
            const float* __restrict__ emb_b,
            float* __restrict__ s2s, float* __restrict__ sdst)
{
    __shared__ _Float16 hsA[16 * 136], hsB[16 * 136];
    const int tid  = threadIdx.x;
    const int lane = tid & 63;
    const int wid  = tid >> 6;
    const int half = wid & 1;
    const int msel = wid >> 1;
    const int rl   = lane & 15;
    const int quad = lane >> 4;
    const int row  = blockIdx.x * 16 + rl;
    const size_t rbase = (size_t)row * H;

    f16x8 bf[4];
#pragma unroll
    for (int kb = 0; kb < 4; ++kb) {
        const int kc = kb * 32 + quad * 8;
        float4 v0 = *(const float4*)(x + rbase + kc);
        float4 v1 = *(const float4*)(x + rbase + kc + 4);
        bf[kb] = (f16x8){(_Float16)v0.x, (_Float16)v0.y, (_Float16)v0.z, (_Float16)v0.w,
                         (_Float16)v1.x, (_Float16)v1.y, (_Float16)v1.z, (_Float16)v1.w};
    }

    const _Float16* wm = wpk + (size_t)msel * 2 * 16384;
    _Float16* strip = msel ? hsB : hsA;
    const float* bias0 = emb_b + msel * 2 * H;

    f32x4 acc[4];
    mfma_layerT<4>(wm, bf, half * 4, lane, acc);
    store_stripT<4>(strip, acc, bias0, half * 4, rl, quad);
    __syncthreads();
    load_bf(strip, bf, rl, quad);
    mfma_layerT<4>(wm + 16384, bf, half * 4, lane, acc);

    float* outp = msel ? sdst : s2s;
    const float* bias1 = bias0 + H;
#pragma unroll
    for (int ctl = 0; ctl < 4; ++ctl) {
        const int c = (half * 4 + ctl) * 16 + quad * 4;
        float4 bb = *(const float4*)(bias1 + c);
        float4 v;
        v.x = silu_f(acc[ctl][0] + bb.x);
        v.y = silu_f(acc[ctl][1] + bb.y);
        v.z = silu_f(acc[ctl][2] + bb.z);
        v.w = silu_f(acc[ctl][3] + bb.w);
        *(float4*)(outp + rbase + c) = v;
    }
}

// ---------------------------------------------------------------------------
// out6_k: fused tail — conv -> residual(conv_w0) -> residual(conv_w1)
//                      -> z = s2s .* conv -> out = z + mlp2(z; out_w)
// 256-thread block = 4 waves, each owns 32 out-cols (ct0 = wid*2, CT=2).
// ---------------------------------------------------------------------------
__global__ __launch_bounds__(256)
void out6_k(const float* __restrict__ conv, const float* __restrict__ s2s,
            const _Float16* __restrict__ w6,   // mats 4..9
            const float* __restrict__ conv_b, const float* __restrict__ out_b,
            float* __restrict__ y)
{
    __shared__ _Float16 hs0[16 * 136], hs1[16 * 136];
    const int tid  = threadIdx.x;
    const int lane = tid & 63;
    const int ct0  = (tid >> 6) * 2;
    const int rl   = lane & 15;
    const int quad = lane >> 4;
    const int row  = blockIdx.x * 16 + rl;
    const size_t rbase = (size_t)row * H;

    f16x8 bf[4];
#pragma unroll
    for (int kb = 0; kb < 4; ++kb) {
        const int kc = kb * 32 + quad * 8;
        float4 v0 = *(const float4*)(conv + rbase + kc);
        float4 v1 = *(const float4*)(conv + rbase + kc + 4);
        bf[kb] = (f16x8){(_Float16)v0.x, (_Float16)v0.y, (_Float16)v0.z, (_Float16)v0.w,
                         (_Float16)v1.x, (_Float16)v1.y, (_Float16)v1.z, (_Float16)v1.w};
    }

    f32x4 acc[2], tD[2];

    // L0: hidden of residual-1
    mfma_layerT<2>(w6, bf, ct0, lane, acc);
    store_stripT<2>(hs0, acc, conv_b, ct0, rl, quad);
    __syncthreads();
    load_bf(hs0, bf, rl, quad);

    // L1: t = conv + mlp_out
    mfma_layerT<2>(w6 + 16384, bf, ct0, lane, acc);
#pragma unroll
    for (int ctl = 0; ctl < 2; ++ctl) {
        const int c = (ct0 + ctl) * 16 + quad * 4;
        float4 bb = *(const float4*)(conv_b + H + c);
        float4 cv = *(const float4*)(conv + rbase + c);
        tD[ctl][0] = cv.x + silu_f(acc[ctl][0] + bb.x);
        tD[ctl][1] = cv.y + silu_f(acc[ctl][1] + bb.y);
        tD[ctl][2] = cv.z + silu_f(acc[ctl][2] + bb.z);
        tD[ctl][3] = cv.w + silu_f(acc[ctl][3] + bb.w);
    }
    store_strip_rawT<2>(hs1, tD, ct0, rl, quad);
    __syncthreads();
    load_bf(hs1, bf, rl, quad);

    // L2: hidden of residual-2
    mfma_layerT<2>(w6 + 2 * 16384, bf, ct0, lane, acc);
    store_stripT<2>(hs0, acc, conv_b + 2 * H, ct0, rl, quad);
    __syncthreads();
    load_bf(hs0, bf, rl, quad);

    // L3: t += mlp_out;  z = t * s2s
    mfma_layerT<2>(w6 + 3 * 16384, bf, ct0, lane, acc);
#pragma unroll
    for (int ctl = 0; ctl < 2; ++ctl) {
        const int c = (ct0 + ctl) * 16 + quad * 4;
        float4 bb = *(const float4*)(conv_b + 3 * H + c);
        float4 sv = *(const float4*)(s2s + rbase + c);
        tD[ctl][0] = (tD[ctl][0] + silu_f(acc[ctl][0] + bb.x)) * sv.x;
        tD[ctl][1] = (tD[ctl][1] + silu_f(acc[ctl][1] + bb.y)) * sv.y;
        tD[ctl][2] = (tD[ctl][2] + silu_f(acc[ctl][2] + bb.z)) * sv.z;
        tD[ctl][3] = (tD[ctl][3] + silu_f(acc[ctl][3] + bb.w)) * sv.w;
    }
    store_strip_rawT<2>(hs1, tD, ct0, rl, quad);
    __syncthreads();
    load_bf(hs1, bf, rl, quad);

    // L4: hidden of final residual
    mfma_layerT<2>(w6 + 4 * 16384, bf, ct0, lane, acc);
    store_stripT<2>(hs0, acc, out_b, ct0, rl, quad);
    __syncthreads();
    load_bf(hs0, bf, rl, quad);

    // L5: out = z + mlp_out
    mfma_layerT<2>(w6 + 5 * 16384, bf, ct0, lane, acc);
#pragma unroll
    for (int ctl = 0; ctl < 2; ++ctl) {
        const int c = (ct0 + ctl) * 16 + quad * 4;
        float4 bb = *(const float4*)(out_b + H + c);
        float4 v;
        v.x = tD[ctl][0] + silu_f(acc[ctl][0] + bb.x);
        v.y = tD[ctl][1] + silu_f(acc[ctl][1] + bb.y);
        v.z = tD[ctl][2] + silu_f(acc[ctl][2] + bb.z);
        v.w = tD[ctl][3] + silu_f(acc[ctl][3] + bb.w);
        *(float4*)(y + rbase + c) = v;
    }
}

// ---------------------------------------------------------------------------
// Counting sort of edges by destination node (flat key = b*N + row)
// ---------------------------------------------------------------------------
__global__ __launch_bounds__(256)
void hist_k(const int* __restrict__ eidx, int* __restrict__ cnt)
{
    const int e = blockIdx.x * 256 + threadIdx.x;       // 640000 exact
    const int row = eidx[2 * (size_t)e];
    const int b = (unsigned)e / 160000u;
    atomicAdd(&cnt[b * 10000 + row], 1);
}

// Single-block exclusive scan of 40960 counters (1024 threads x 40 elements).
__global__ __launch_bounds__(1024)
void scan_k(const int* __restrict__ cnt, int* __restrict__ offs,
            int* __restrict__ cursor)
{
    __shared__ int sh[1024];
    const int t = threadIdx.x;
    const int base = t * 40;
    int vals[40];
    int s = 0;
#pragma unroll
    for (int i = 0; i < 40; ++i) { vals[i] = cnt[base + i]; s += vals[i]; }
    sh[t] = s;
    __syncthreads();
    for (int off = 1; off < 1024; off <<= 1) {
        int v = (t >= off) ? sh[t - off] : 0;
        __syncthreads();
        sh[t] += v;
        __syncthreads();
    }
    int run = (t > 0) ? sh[t - 1] : 0;
#pragma unroll
    for (int i = 0; i < 40; ++i) {
        offs[base + i] = run;
        cursor[base + i] = run;
        run += vals[i];
    }
    if (t == 1023) offs[40960] = run;
}

__global__ __launch_bounds__(256)
void scatter_k(const int* __restrict__ eidx, int* __restrict__ cursor,
               int2* __restrict__ meta)
{
    const int e = blockIdx.x * 256 + threadIdx.x;       // 640000 exact
    const int2 rc = ((const int2*)eidx)[e];
    const int b = (unsigned)e / 160000u;
    const int pos = atomicAdd(&cursor[b * 10000 + rc.x], 1);
    meta[pos] = make_int2(e, b * 10000 + rc.y);
}

// ---------------------------------------------------------------------------
// Gather-reduce v5: 1 wave per node; ew held in 64 VGPRs (launch_bounds caps
// occupancy so the compiler keeps the array resident); 2-edge manual unroll.
// ---------------------------------------------------------------------------
__device__ __forceinline__ f32x2 edge_term(const float* __restrict__ ef,
                                           const float* __restrict__ sdst,
                                           const f32x2 ewr[32],
                                           int e, int sc, int lane)
{
    const float4* p = (const float4*)(ef + (size_t)e * 32);
    const f32x2 g = *(const f32x2*)(sdst + (size_t)sc * H + lane * 2);
    f32x2 s0 = {0.f, 0.f}, s1 = {0.f, 0.f};
#pragma unroll
    for (int kb = 0; kb < 8; ++kb) {
        const float4 q = p[kb];
        s0 += (f32x2){q.x, q.x} * ewr[kb * 4 + 0] + (f32x2){q.z, q.z} * ewr[kb * 4 + 2];
        s1 += (f32x2){q.y, q.y} * ewr[kb * 4 + 1] + (f32x2){q.w, q.w} * ewr[kb * 4 + 3];
    }
    return g * (s0 + s1);
}

__global__ __launch_bounds__(256, 3)
void conv_k(const float* __restrict__ ef, const float* __restrict__ sdst,
            const float* __restrict__ ew, const float* __restrict__ C,
            const int* __restrict__ offs, const int2* __restrict__ meta,
            float* __restrict__ conv)
{
    const int lane = threadIdx.x & 63;
    const int nid  = blockIdx.x * 4 + (threadIdx.x >> 6);   // 10000 blocks

    f32x2 ewr[32];
#pragma unroll
    for (int k = 0; k < 32; ++k)
        ewr[k] = *(const f32x2*)(ew + k * H + lane * 2);

    const int start = offs[nid], end = offs[nid + 1];
    f32x2 acc = {0.f, 0.f};
    for (int base = start; base < end; base += 64) {
        const int cnt = min(64, end - base);
        int2 md = make_int2(0, 0);
        if (lane < cnt) md = meta[base + lane];
        int j = 0;
        for (; j + 2 <= cnt; j += 2) {
            const int e0  = __builtin_amdgcn_readlane(md.x, j);
            const int sc0 = __builtin_amdgcn_readlane(md.y, j);
            const int e1  = __builtin_amdgcn_readlane(md.x, j + 1);
            const int sc1 = __builtin_amdgcn_readlane(md.y, j + 1);
            acc += edge_term(ef, sdst, ewr, e0, sc0, lane)
                 + edge_term(ef, sdst, ewr, e1, sc1, lane);
        }
        if (j < cnt) {
            const int e0  = __builtin_amdgcn_readlane(md.x, j);
            const int sc0 = __builtin_amdgcn_readlane(md.y, j);
            acc += edge_term(ef, sdst, ewr, e0, sc0, lane);
        }
    }
    const float Cb = C[(unsigned)nid / 10000u];
    f32x2 st = acc * Cb;
    *(f32x2*)(conv + (size_t)nid * H + lane * 2) = st;
}

// ---------------------------------------------------------------------------
extern "C" void kernel_launch(void* const* d_in, const int* in_sizes, int n_in,
                              void* d_out, int out_size, void* d_ws, size_t ws_size,
                              hipStream_t stream)
{
    const float* scalar = (const float*)d_in[0];
    const float* ef     = (const float*)d_in[1];
    const int*   eidx   = (const int*)d_in[2];
    const float* C      = (const float*)d_in[3];
    const float* emb_w  = (const float*)d_in[4];
    const float* emb_b  = (const float*)d_in[5];
    const float* e_w    = (const float*)d_in[6];
    const float* conv_w = (const float*)d_in[7];
    const float* conv_b = (const float*)d_in[8];
    const float* out_w  = (const float*)d_in[9];
    const float* out_b  = (const float*)d_in[10];

    const int M = 40000;
    const size_t nodeElems = (size_t)M * H;            // 5,120,000

    float* s2s  = (float*)d_ws;
    float* sdst = s2s + nodeElems;
    float* conv = sdst + nodeElems;
    _Float16* wpk = (_Float16*)(conv + nodeElems);     // 163840 halves
    int* cnt    = (int*)(wpk + 163840);                // 40960
    int* offs   = cnt + 40960;                         // 40961 (+pad)
    int* cursor = offs + 40964;                        // 40960
    int2* meta  = (int2*)(cursor + 40960);             // 640000 int2

    dim3 blk(256);

    pack_w<<<80, blk, 0, stream>>>(emb_w, conv_w, out_w, wpk, cnt);
    // s2s + scalar_dst in one pass
    emb2_k<<<2500, blk, 0, stream>>>(scalar, wpk, emb_b, s2s, sdst);
    // counting sort of edges by destination
    hist_k<<<2500, blk, 0, stream>>>(eidx, cnt);
    scan_k<<<1, 1024, 0, stream>>>(cnt, offs, cursor);
    scatter_k<<<2500, blk, 0, stream>>>(eidx, cursor, meta);
    // conv = C * segment_sum(gather(sdst,col) * ef@e_w, row)
    conv_k<<<10000, blk, 0, stream>>>(ef, sdst, e_w, C, offs, meta, conv);
    // fused tail
    out6_k<<<2500, blk, 0, stream>>>(conv, s2s, wpk + 4 * 16384,
                                     conv_b, out_b, (float*)d_out);
}